// Round 2
// baseline (15081.573 us; speedup 1.0000x reference)
//
#include <hip/hip_runtime.h>
#include <hip/hip_fp16.h>

typedef unsigned int u32;
typedef _Float16 half2v __attribute__((ext_vector_type(2)));

#define N_UNITS 512
#define N_ORDER 256
#define N_T     1024
#define N_B     64

__device__ inline float dot2f(u32 a, u32 b, float acc) {
#if __has_builtin(__builtin_amdgcn_fdot2)
    return __builtin_amdgcn_fdot2(__builtin_bit_cast(half2v, a),
                                  __builtin_bit_cast(half2v, b), acc, false);
#else
    half2v av = __builtin_bit_cast(half2v, a);
    half2v bv = __builtin_bit_cast(half2v, b);
    return acc + (float)av[0] * (float)bv[0] + (float)av[1] * (float)bv[1];
#endif
}

__device__ inline u32 pack_h2(float a, float b) {
    __half ha = __float2half(a), hb = __float2half(b);
    return (u32)__half_as_ushort(ha) | ((u32)__half_as_ushort(hb) << 16);
}

// Pack weights:
//  hk2[kk][c] = half2(hk[2kk][c], hk[2kk+1][c])    kk<256, c<512   (fp16)
//  mk2[kk][c] = half2(mk[2kk][c], mk[2kk+1][c])    kk<128, c<512   (fp16)
//  at2f[kk][j] = float2(AT[2kk][j], AT[2kk+1][j])  kk<128, j<256   (fp32!)
__global__ __launch_bounds__(256)
void prep_weights(const float* __restrict__ hk, const float* __restrict__ mk,
                  const float* __restrict__ at,
                  u32* __restrict__ hk2, u32* __restrict__ mk2,
                  float2* __restrict__ at2f) {
    int tid = blockIdx.x * 256 + threadIdx.x;
    const int HK_N = 256 * 512, MK_N = 128 * 512, AT_N = 128 * 256;
    if (tid < HK_N) {
        int kk = tid >> 9, c = tid & 511;
        hk2[tid] = pack_h2(hk[(2 * kk) * 512 + c], hk[(2 * kk + 1) * 512 + c]);
    } else if (tid < HK_N + MK_N) {
        int r = tid - HK_N;
        int kk = r >> 9, c = r & 511;
        mk2[r] = pack_h2(mk[(2 * kk) * 512 + c], mk[(2 * kk + 1) * 512 + c]);
    } else if (tid < HK_N + MK_N + AT_N) {
        int r = tid - HK_N - MK_N;
        int kk = r >> 8, j = r & 255;
        at2f[r] = make_float2(at[(2 * kk) * 256 + j], at[(2 * kk + 1) * 256 + j]);
    }
}

// One workgroup per batch element. 512 threads:
//   tid: p = tid&255 (owns h cols 2p,2p+1 / m col p), kh = tid>>8 (K-split half).
// State: h fp32 in regs of tid<256 + fp16 copy in LDS;
//        m fp32 master in LDS + fp16 hi/lo mantissa-split copies in LDS.
// Precision plan: m@AT fully fp32 (marginally stable recurrence — fp16 there
// compounds over 1024 steps); m@mk uses hi+lo fp16 split (m exact to ~fp29);
// h@hk single fp16 (|h|<=1, error 2.4e-4, contractive path).
__global__ __launch_bounds__(512, 1)
void lmu_main(const float* __restrict__ x, const float* __restrict__ ie,
              const float* __restrict__ he, const float* __restrict__ me,
              const float* __restrict__ ik, const float* __restrict__ bt,
              const u32* __restrict__ hk2, const u32* __restrict__ mk2,
              const float2* __restrict__ at2f, float* __restrict__ out) {
    __shared__ float xs[N_T];
    __shared__ float he_s[N_UNITS], ik_s[N_UNITS];
    __shared__ float me_s[N_ORDER], bt_s[N_ORDER];
    __shared__ u32   h2u[N_UNITS / 2];            // fp16 h state (pairs)
    __shared__ u32   m2u[N_ORDER / 2];            // fp16 m hi (pairs)
    __shared__ u32   m2l[N_ORDER / 2];            // fp16 m lo residual (pairs)
    __shared__ __align__(8) float mf[N_ORDER];    // fp32 m state
    __shared__ float ampart[512];                 // AT-dot partials
    __shared__ float2 zbuf[512];                  // z partials
    __shared__ float red[8];                      // u reduction

    const int tid  = threadIdx.x;
    const int b    = blockIdx.x;
    const int p    = tid & 255;
    const int kh   = tid >> 8;   // 0 or 1
    const int lane = tid & 63;
    const int wv   = tid >> 6;

    // ---- preload ----
    for (int i = tid; i < N_T; i += 512) xs[i] = x[b * N_T + i];
    if (tid < N_UNITS) { he_s[tid] = he[tid]; ik_s[tid] = ik[tid]; }
    if (tid < N_ORDER) { me_s[tid] = me[tid]; bt_s[tid] = bt[tid]; mf[tid] = 0.f; }
    if (tid < N_UNITS / 2) h2u[tid] = 0u;
    if (tid < N_ORDER / 2) { m2u[tid] = 0u; m2l[tid] = 0u; }
    const float ie0 = ie[0];
    __syncthreads();

    float hr0 = 0.f, hr1 = 0.f;  // h[2p], h[2p+1] for tid<256

    const float2* at_base = at2f + (size_t)(kh * 64) * 256 + p;      // stride 256 per kk
    const u32*    hk_base = hk2 + (size_t)(kh * 128) * 512 + 2 * p;  // stride 512 per kk
    const u32*    mk_base = mk2 + (size_t)(kh * 64) * 512 + 2 * p;   // stride 512 per kk
    const float2* mf2 = reinterpret_cast<const float2*>(mf);
    float* outb = out + (size_t)b * N_T * N_UNITS;

    for (int t = 0; t < N_T; ++t) {
        // ---- phase 1: u partials (OLD h, OLD m) ----
        float up = 0.f;
        if (tid < 256) {
            up = hr0 * he_s[2 * p] + hr1 * he_s[2 * p + 1] + mf[p] * me_s[p];
        }
        #pragma unroll
        for (int off = 32; off > 0; off >>= 1) up += __shfl_down(up, off);
        if (lane == 0) red[wv] = up;

        // ---- phase 2: m@AT partials, FP32 (OLD m) ----
        {
            float am = 0.f;
            #pragma unroll 16
            for (int i = 0; i < 64; ++i) {
                float2 w  = at_base[(size_t)i * 256];
                float2 mm = mf2[kh * 64 + i];
                am = fmaf(mm.x, w.x, am);
                am = fmaf(mm.y, w.y, am);
            }
            ampart[tid] = am;
        }
        __syncthreads();  // red + ampart visible; all old-m reads done

        const float u = red[0] + red[1] + red[2] + red[3] +
                        red[4] + red[5] + red[6] + red[7] + xs[t] * ie0;

        // ---- phase 3: m update (fp32) + hi/lo fp16 split ----
        if (tid < 256) {
            float nm = mf[tid] + ampart[tid] + ampart[tid + 256] + u * bt_s[tid];
            mf[tid] = nm;
            __half hi = __float2half(nm);
            float lo = nm - __half2float(hi);
            reinterpret_cast<__half*>(m2u)[tid] = hi;
            reinterpret_cast<__half*>(m2l)[tid] = __float2half(lo);
        }
        __syncthreads();  // new m visible

        // ---- phase 4: z = h_old@hk + m_new@mk partials (fp16 dot2) ----
        {
            float z0 = 0.f, z1 = 0.f;
            #pragma unroll 8
            for (int i = 0; i < 128; ++i) {
                uint2 w = *reinterpret_cast<const uint2*>(hk_base + (size_t)i * 512);
                u32 hh = h2u[kh * 128 + i];
                z0 = dot2f(hh, w.x, z0);
                z1 = dot2f(hh, w.y, z1);
            }
            #pragma unroll 8
            for (int i = 0; i < 64; ++i) {
                uint2 w = *reinterpret_cast<const uint2*>(mk_base + (size_t)i * 512);
                u32 mm = m2u[kh * 64 + i];
                u32 ml = m2l[kh * 64 + i];
                z0 = dot2f(mm, w.x, z0);
                z0 = dot2f(ml, w.x, z0);
                z1 = dot2f(mm, w.y, z1);
                z1 = dot2f(ml, w.y, z1);
            }
            zbuf[tid] = make_float2(z0, z1);
        }
        __syncthreads();  // zbuf visible; all old-h reads done

        // ---- phase 5: combine, tanh, commit h, write output ----
        if (tid < 256) {
            float z0 = zbuf[tid].x + zbuf[tid + 256].x + xs[t] * ik_s[2 * tid];
            float z1 = zbuf[tid].y + zbuf[tid + 256].y + xs[t] * ik_s[2 * tid + 1];
            hr0 = tanhf(z0);
            hr1 = tanhf(z1);
            h2u[tid] = pack_h2(hr0, hr1);
            *reinterpret_cast<float2*>(outb + (size_t)t * N_UNITS + 2 * tid) =
                make_float2(hr0, hr1);
        }
        // next iteration's phase-2 barrier orders h2u write vs phase-4 reads
    }
}

extern "C" void kernel_launch(void* const* d_in, const int* in_sizes, int n_in,
                              void* d_out, int out_size, void* d_ws, size_t ws_size,
                              hipStream_t stream) {
    const float* x  = (const float*)d_in[0];
    const float* ie = (const float*)d_in[1];
    const float* he = (const float*)d_in[2];
    const float* me = (const float*)d_in[3];
    const float* ik = (const float*)d_in[4];
    const float* hk = (const float*)d_in[5];
    const float* mk = (const float*)d_in[6];
    const float* at = (const float*)d_in[7];
    const float* bt = (const float*)d_in[8];

    u32*    hk2  = (u32*)d_ws;                       // 256*512*4B  = 512 KB
    u32*    mk2  = hk2 + 256 * 512;                  // 128*512*4B  = 256 KB
    float2* at2f = (float2*)(mk2 + 128 * 512);       // 128*256*8B  = 256 KB

    const int total = 256 * 512 + 128 * 512 + 128 * 256;  // 229376
    prep_weights<<<(total + 255) / 256, 256, 0, stream>>>(hk, mk, at, hk2, mk2, at2f);
    lmu_main<<<N_B, 512, 0, stream>>>(x, ie, he, me, ik, bt, hk2, mk2, at2f,
                                      (float*)d_out);
}

// Round 3
// 9560.222 us; speedup vs baseline: 1.5775x; 1.5775x over previous
//
#include <hip/hip_runtime.h>
#include <hip/hip_fp16.h>

typedef unsigned int u32;
typedef _Float16 half2v __attribute__((ext_vector_type(2)));

#define N_UNITS 512
#define N_ORDER 256
#define N_T     1024
#define N_B     64
#define KWG     4

__device__ inline float dot2f(u32 a, u32 b, float acc) {
#if __has_builtin(__builtin_amdgcn_fdot2)
    return __builtin_amdgcn_fdot2(__builtin_bit_cast(half2v, a),
                                  __builtin_bit_cast(half2v, b), acc, false);
#else
    half2v av = __builtin_bit_cast(half2v, a);
    half2v bv = __builtin_bit_cast(half2v, b);
    return acc + (float)av[0] * (float)bv[0] + (float)av[1] * (float)bv[1];
#endif
}

__device__ inline u32 pack_h2(float a, float b) {
    __half ha = __float2half(a), hb = __float2half(b);
    return (u32)__half_as_ushort(ha) | ((u32)__half_as_ushort(hb) << 16);
}

// Pack hk/mk into k-pair half2 layout (fp16); zero the sync flags.
//  hk2[kk][c] = half2(hk[2kk][c], hk[2kk+1][c])  kk<256, c<512
//  mk2[kk][c] = half2(mk[2kk][c], mk[2kk+1][c])  kk<128, c<512
__global__ __launch_bounds__(256)
void prep_weights(const float* __restrict__ hk, const float* __restrict__ mk,
                  u32* __restrict__ hk2, u32* __restrict__ mk2,
                  u32* __restrict__ flags /* 512 entries: flagA(256), flagB(256) */) {
    int tid = blockIdx.x * 256 + threadIdx.x;
    const int HK_N = 256 * 512, MK_N = 128 * 512;
    if (tid < HK_N) {
        int kk = tid >> 9, c = tid & 511;
        hk2[tid] = pack_h2(hk[(2 * kk) * 512 + c], hk[(2 * kk + 1) * 512 + c]);
    } else if (tid < HK_N + MK_N) {
        int r = tid - HK_N;
        int kk = r >> 9, c = r & 511;
        mk2[r] = pack_h2(mk[(2 * kk) * 512 + c], mk[(2 * kk + 1) * 512 + c]);
    }
    if (tid < 2 * N_B * KWG) {
        // write-through to coherence point so cross-XCD acquire loads see 0
        __hip_atomic_store(&flags[tid], 0u, __ATOMIC_RELAXED, __HIP_MEMORY_SCOPE_AGENT);
    }
}

// K=4 workgroups per batch element; grid = 256 (one WG per CU, all co-resident).
// blockIdx g: b = g & 63, q = g >> 6  (all q of a batch share XCD under %8 RR).
// WG q owns h cols [128q,128q+128) and m cols [64q,64q+64).
// Weights VGPR-resident: hk slice 64 u32, mk slice 32 u32, AT slice 32 fp32.
// Per-step cross-WG exchange via agent-scope atomics + epoch flags:
//   sync A: m_new slices (overlapped with h@hk product)
//   sync B: h_new slices + u partials
__global__ __launch_bounds__(512, 1)
void lmu_main(const float* __restrict__ x, const float* __restrict__ ie,
              const float* __restrict__ he, const float* __restrict__ me,
              const float* __restrict__ ik, const float* __restrict__ bt,
              const float* __restrict__ at,
              const u32* __restrict__ hk2, const u32* __restrict__ mk2,
              float* __restrict__ m_glob, u32* __restrict__ h_glob,
              float* __restrict__ ug, u32* __restrict__ flagA,
              u32* __restrict__ flagB, float* __restrict__ out) {
    __shared__ float xs[N_T];
    __shared__ float he_s[N_UNITS], ik_s[N_UNITS];
    __shared__ float me_s[N_ORDER], bt_s[N_ORDER];
    __shared__ __half h_h[N_UNITS];              // full h state, fp16
    __shared__ float  mf[N_ORDER];               // full m state, fp32
    __shared__ __half m_hi[N_ORDER], m_lo[N_ORDER];
    __shared__ float ampart[512];
    __shared__ float zbuf[512];
    __shared__ float red4s[KWG];
    __shared__ float upw[2];

    const int tid  = threadIdx.x;
    const int g    = blockIdx.x;
    const int b    = g & 63;
    const int q    = g >> 6;
    const int kg   = tid >> 7;       // 0..3  (hk/mk k-group)
    const int cl   = tid & 127;      // col within h slice
    const int C    = 128 * q + cl;
    const int kg8  = tid >> 6;       // 0..7  (AT k-group)
    const int jl   = tid & 63;
    const int J    = 64 * q + jl;
    const int lane = tid & 63;

    // ---- LDS preload ----
    for (int i = tid; i < N_T; i += 512) xs[i] = x[b * N_T + i];
    if (tid < N_UNITS) { he_s[tid] = he[tid]; ik_s[tid] = ik[tid]; }
    if (tid < N_ORDER) {
        me_s[tid] = me[tid]; bt_s[tid] = bt[tid];
        mf[tid] = 0.f;
        m_hi[tid] = __float2half(0.f);
        m_lo[tid] = __float2half(0.f);
    }
    h_h[tid] = __float2half(0.f);
    if (tid < KWG) red4s[tid] = 0.f;
    const float ie0 = ie[0];

    // ---- weights into registers (once) ----
    u32 hk_w[64];
    #pragma unroll
    for (int i = 0; i < 64; ++i) hk_w[i] = hk2[(size_t)(64 * kg + i) * 512 + C];
    u32 mk_w[32];
    #pragma unroll
    for (int i = 0; i < 32; ++i) mk_w[i] = mk2[(size_t)(32 * kg + i) * 512 + C];
    float at_w[32];
    #pragma unroll
    for (int i = 0; i < 32; ++i) at_w[i] = at[(size_t)(32 * kg8 + i) * 256 + J];

    __syncthreads();

    const u32* h2u = reinterpret_cast<const u32*>(h_h);
    const u32* m2u = reinterpret_cast<const u32*>(m_hi);
    const u32* m2l = reinterpret_cast<const u32*>(m_lo);

    // peer flag indices for the 3 spin threads
    const int qp = (tid < 3) ? (tid + (tid >= q ? 1 : 0)) : 0;
    const int fpeer = b * KWG + qp;
    const int fmine = b * KWG + q;

    float* outb = out + (size_t)b * N_T * N_UNITS;
    float* mgb  = m_glob + b * N_ORDER;
    u32*   hgb  = h_glob + b * N_ORDER;   // stored as 64 u32 pairs per slice... (256 total)

    for (int t = 0; t < N_T; ++t) {
        // u(t) from staged partials (h_{t-1}, m_{t-1}) + input
        const float u = red4s[0] + red4s[1] + red4s[2] + red4s[3] + xs[t] * ie0;

        // ---- AT partials over m_old (fp32, VGPR weights) ----
        float am = 0.f;
        #pragma unroll
        for (int i = 0; i < 32; ++i) am = fmaf(mf[32 * kg8 + i], at_w[i], am);
        ampart[tid] = am;
        __syncthreads();                                   // B1

        // ---- m_new own slice: reduce 8 partials, publish ----
        float mnew = 0.f;
        if (tid < 64) {
            mnew = mf[J] + u * bt_s[J];
            #pragma unroll
            for (int gi = 0; gi < 8; ++gi) mnew += ampart[tid + 64 * gi];
            __hip_atomic_store(&mgb[J], mnew, __ATOMIC_RELAXED, __HIP_MEMORY_SCOPE_AGENT);
            // local LDS update of own slice (peers staged after sync A)
            mf[J] = mnew;
            __half hi = __float2half(mnew);
            m_hi[J] = hi;
            m_lo[J] = __float2half(mnew - __half2float(hi));
        }
        __syncthreads();                                   // B2 (drains vmem stores)
        if (tid == 0)
            __hip_atomic_store(&flagA[fmine], (u32)(t + 1),
                               __ATOMIC_RELEASE, __HIP_MEMORY_SCOPE_AGENT);

        // ---- h_old @ hk slice (overlaps peers' m publication) ----
        float z = 0.f;
        #pragma unroll
        for (int i = 0; i < 64; ++i) z = dot2f(h2u[64 * kg + i], hk_w[i], z);

        // ---- sync A: wait peers' m slices ----
        if (tid < 3) {
            while (__hip_atomic_load(&flagA[fpeer], __ATOMIC_ACQUIRE,
                                     __HIP_MEMORY_SCOPE_AGENT) < (u32)(t + 1)) {}
        }
        __syncthreads();                                   // B3

        // ---- stage peers' m_new (192 words) ----
        if (tid < 192) {
            int pi = tid >> 6, w = tid & 63;
            int q2 = pi + (pi >= q ? 1 : 0);
            int idx = 64 * q2 + w;
            float v = __hip_atomic_load(&mgb[idx], __ATOMIC_RELAXED,
                                        __HIP_MEMORY_SCOPE_AGENT);
            mf[idx] = v;
            __half hi = __float2half(v);
            m_hi[idx] = hi;
            m_lo[idx] = __float2half(v - __half2float(hi));
        }
        __syncthreads();                                   // B4

        // ---- m_new @ mk slice (hi/lo fp16 split) ----
        #pragma unroll
        for (int i = 0; i < 32; ++i) {
            u32 w = mk_w[i];
            z = dot2f(m2u[32 * kg + i], w, z);
            z = dot2f(m2l[32 * kg + i], w, z);
        }
        zbuf[tid] = z;
        __syncthreads();                                   // B5

        // ---- finalize h cols, write out, u partial ----
        float up = 0.f;
        if (tid < 128) {
            float zf = zbuf[tid] + zbuf[tid + 128] + zbuf[tid + 256] + zbuf[tid + 384]
                     + xs[t] * ik_s[128 * q + tid];
            float hnew = tanhf(zf);
            outb[(size_t)t * N_UNITS + 128 * q + tid] = hnew;
            h_h[128 * q + tid] = __float2half(hnew);
            up = hnew * he_s[128 * q + tid];
            if (tid < 64) up = fmaf(mnew, me_s[J], up);
        }
        #pragma unroll
        for (int off = 32; off > 0; off >>= 1) up += __shfl_down(up, off);
        if (lane == 0 && tid < 128) upw[tid >> 6] = up;
        __syncthreads();                                   // B6

        if (t < N_T - 1) {
            // ---- publish h slice (as pairs) + u partial ----
            if (tid < 64) {
                u32 hp = pack_h2(__half2float(h_h[128 * q + 2 * tid]),
                                 __half2float(h_h[128 * q + 2 * tid + 1]));
                __hip_atomic_store(&hgb[64 * q + tid], hp, __ATOMIC_RELAXED,
                                   __HIP_MEMORY_SCOPE_AGENT);
            }
            if (tid == 0)
                __hip_atomic_store(&ug[fmine], upw[0] + upw[1], __ATOMIC_RELAXED,
                                   __HIP_MEMORY_SCOPE_AGENT);
            __syncthreads();                               // B7 (drains vmem stores)
            if (tid == 0)
                __hip_atomic_store(&flagB[fmine], (u32)(t + 1),
                                   __ATOMIC_RELEASE, __HIP_MEMORY_SCOPE_AGENT);
            if (tid < 3) {
                while (__hip_atomic_load(&flagB[fpeer], __ATOMIC_ACQUIRE,
                                         __HIP_MEMORY_SCOPE_AGENT) < (u32)(t + 1)) {}
            }
            __syncthreads();                               // B8

            // ---- stage peers' h + all u partials ----
            if (tid < 192) {
                int pi = tid >> 6, w = tid & 63;
                int q2 = pi + (pi >= q ? 1 : 0);
                u32 hp = __hip_atomic_load(&hgb[64 * q2 + w], __ATOMIC_RELAXED,
                                           __HIP_MEMORY_SCOPE_AGENT);
                reinterpret_cast<u32*>(h_h)[64 * q2 + w] = hp;
            }
            if (tid < KWG)
                red4s[tid] = __hip_atomic_load(&ug[b * KWG + tid], __ATOMIC_RELAXED,
                                               __HIP_MEMORY_SCOPE_AGENT);
            __syncthreads();                               // B9
        }
    }
}

extern "C" void kernel_launch(void* const* d_in, const int* in_sizes, int n_in,
                              void* d_out, int out_size, void* d_ws, size_t ws_size,
                              hipStream_t stream) {
    const float* x  = (const float*)d_in[0];
    const float* ie = (const float*)d_in[1];
    const float* he = (const float*)d_in[2];
    const float* me = (const float*)d_in[3];
    const float* ik = (const float*)d_in[4];
    const float* hk = (const float*)d_in[5];
    const float* mk = (const float*)d_in[6];
    const float* at = (const float*)d_in[7];
    const float* bt = (const float*)d_in[8];

    // ws layout
    u32*   hk2    = (u32*)d_ws;                    // 256*512 u32 = 512 KB
    u32*   mk2    = hk2 + 256 * 512;               // 128*512 u32 = 256 KB
    float* m_glob = (float*)(mk2 + 128 * 512);     // 64*256 f    = 64 KB
    u32*   h_glob = (u32*)(m_glob + N_B * N_ORDER);// 64*256 u32  = 64 KB
    float* ug     = (float*)(h_glob + N_B * N_ORDER); // 64*4 f   = 1 KB
    u32*   flags  = (u32*)(ug + N_B * KWG);        // 512 u32     = 2 KB
    u32*   flagA  = flags;
    u32*   flagB  = flags + N_B * KWG;

    const int total = 256 * 512 + 128 * 512;       // 196608
    prep_weights<<<(total + 255) / 256, 256, 0, stream>>>(hk, mk, hk2, mk2, flags);
    lmu_main<<<N_B * KWG, 512, 0, stream>>>(x, ie, he, me, ik, bt, at, hk2, mk2,
                                            m_glob, h_glob, ug, flagA, flagB,
                                            (float*)d_out);
}

// Round 4
// 2903.348 us; speedup vs baseline: 5.1945x; 3.2928x over previous
//
#include <hip/hip_runtime.h>
#include <hip/hip_fp16.h>

typedef unsigned int u32;
typedef unsigned short u16;
typedef _Float16 half2v __attribute__((ext_vector_type(2)));

#define N_UNITS 512
#define N_ORDER 256
#define N_T     1024
#define N_B     64
#define KWG     4
#define PKT_STRIDE 288   // dwords per (parity,b,q) packet: 128 m + 128 h + 2 u + pad

__device__ inline float dot2f(u32 a, u32 b, float acc) {
    return __builtin_amdgcn_fdot2(__builtin_bit_cast(half2v, a),
                                  __builtin_bit_cast(half2v, b), acc, false);
}
__device__ inline u16 f2h_bits(float v) {
    _Float16 f = (_Float16)v;
    return __builtin_bit_cast(u16, f);
}
__device__ inline float hbits2f(u32 dw) {
    u16 s = (u16)(dw & 0xFFFFu);
    _Float16 f = __builtin_bit_cast(_Float16, s);
    return (float)f;
}
__device__ inline u32 pack_h2(float a, float b) {
    return (u32)f2h_bits(a) | ((u32)f2h_bits(b) << 16);
}
__device__ inline u32 aload(const u32* p) {
    return __hip_atomic_load(p, __ATOMIC_RELAXED, __HIP_MEMORY_SCOPE_AGENT);
}
__device__ inline void astore(u32* p, u32 v) {
    __hip_atomic_store(p, v, __ATOMIC_RELAXED, __HIP_MEMORY_SCOPE_AGENT);
}

// hk2[kk][c] = half2(hk[2kk][c], hk[2kk+1][c]),  kk<256, c<512
__global__ __launch_bounds__(256)
void prep_hk(const float* __restrict__ hk, u32* __restrict__ hk2) {
    int tid = blockIdx.x * 256 + threadIdx.x;   // 131072 total
    int kk = tid >> 9, c = tid & 511;
    hk2[tid] = pack_h2(hk[(2 * kk) * 512 + c], hk[(2 * kk + 1) * 512 + c]);
}

// AMK = mk + AT@mk  (fp16, j-pair packed);  BMK = BT@mk (fp32)
// blocks 0..127: amk2[bj][c] = half2(AMK[2bj][c], AMK[2bj+1][c]); block 128: BMK
__global__ __launch_bounds__(512)
void prep_amk(const float* __restrict__ mk, const float* __restrict__ at,
              const float* __restrict__ bt,
              u32* __restrict__ amk2, float* __restrict__ bmk) {
    int bj = blockIdx.x, c = threadIdx.x;
    if (bj < 128) {
        int j0 = 2 * bj, j1 = j0 + 1;
        float a0 = mk[j0 * 512 + c];
        float a1 = mk[j1 * 512 + c];
        #pragma unroll 8
        for (int k = 0; k < 256; ++k) {
            float w = mk[k * 512 + c];
            a0 = fmaf(at[j0 * 256 + k], w, a0);
            a1 = fmaf(at[j1 * 256 + k], w, a1);
        }
        amk2[bj * 512 + c] = pack_h2(a0, a1);
    } else {
        float s = 0.f;
        #pragma unroll 8
        for (int k = 0; k < 256; ++k) s = fmaf(bt[k], mk[k * 512 + c], s);
        bmk[c] = s;
    }
}

// K=4 WGs per batch; grid=256 (1 WG/CU). g: b=g&63, q=g>>6 (same XCD mod-8).
// WG q owns h cols [128q,128q+128), m cols [64q,64q+64).
// Weights in VGPRs: hk 64 u32 + AMK 32 u32 + AT 32 f32.
// One cross-WG sync/step via self-validating packets (epoch in each dword's
// high16, dword stores are atomic) — no flags, no release, no producer drain.
// z refactor: m_new@mk = m_old@AMK + u*BMK with AMK = mk + AT@mk.
__global__ __launch_bounds__(512, 2)
void lmu_main(const float* __restrict__ x, const float* __restrict__ ie,
              const float* __restrict__ he, const float* __restrict__ me,
              const float* __restrict__ ik, const float* __restrict__ bt,
              const float* __restrict__ at,
              const u32* __restrict__ hk2, const u32* __restrict__ amk2,
              const float* __restrict__ bmk,
              u32* __restrict__ pkt, float* __restrict__ out) {
    __shared__ float xs[N_T];
    __shared__ float he_sl[128], ik_sl[128], bmk_sl[128];
    __shared__ float me_sl[64], bt_sl[64];
    __shared__ __align__(8) u16 h_h16[N_UNITS];     // full h, fp16
    __shared__ __align__(8) u16 m_hi16[N_ORDER], m_lo16[N_ORDER];
    __shared__ __align__(8) float mf[N_ORDER];      // full m, fp32(-ish)
    __shared__ float zbuf[512], ampart[512];
    __shared__ float upart[4];                      // u partials per q
    __shared__ float upw[2];

    const int tid = threadIdx.x;
    const int g   = blockIdx.x;
    const int b   = g & 63;
    const int q   = g >> 6;
    const int kg  = tid >> 7;        // 0..3 (hk/AMK k-group)
    const int cl  = tid & 127;       // col within own h slice
    const int kg8 = tid >> 6;        // 0..7 (AT k-group)
    const int jl  = tid & 63;
    const int J   = 64 * q + jl;
    const int lane = tid & 63;

    // ---- preload LDS ----
    for (int i = tid; i < N_T; i += 512) xs[i] = x[b * N_T + i];
    if (tid < 128) {
        he_sl[tid]  = he[128 * q + tid];
        ik_sl[tid]  = ik[128 * q + tid];
        bmk_sl[tid] = bmk[128 * q + tid];
    }
    if (tid < 64) { me_sl[tid] = me[J]; bt_sl[tid] = bt[J]; }
    h_h16[tid] = 0;
    if (tid < 256) { m_hi16[tid] = 0; m_lo16[tid] = 0; mf[tid] = 0.f; }
    if (tid < 4) upart[tid] = 0.f;
    const float ie0 = ie[0];

    // ---- weights into registers (once) ----
    u32 hk_w[64];
    #pragma unroll
    for (int i = 0; i < 64; ++i)
        hk_w[i] = hk2[(size_t)(64 * kg + i) * 512 + 128 * q + cl];
    u32 amk_w[32];
    #pragma unroll
    for (int i = 0; i < 32; ++i)
        amk_w[i] = amk2[(size_t)(32 * kg + i) * 512 + 128 * q + cl];
    float at_w[32];
    #pragma unroll
    for (int i = 0; i < 32; ++i)
        at_w[i] = at[(size_t)(32 * kg8 + i) * 256 + J];

    __syncthreads();

    const u32* h2u   = reinterpret_cast<const u32*>(h_h16);
    const u32* m_hi2 = reinterpret_cast<const u32*>(m_hi16);
    const u32* m_lo2 = reinterpret_cast<const u32*>(m_lo16);
    float* outb = out + (size_t)b * N_T * N_UNITS;

    for (int t = 0; t < N_T; ++t) {
        // ---- consume peers' packets (h_{t-1}, m_{t-1}, u-partials) ----
        if (t > 0) {
            const u32 ep  = (u32)t;
            const int par = (t - 1) & 1;
            if (tid < 195) {
                int pi = (tid < 192) ? (tid >> 6) : (tid - 192);
                int q2 = pi + (pi >= q ? 1 : 0);
                const u32* base = pkt + (size_t)(par * 256 + b * 4 + q2) * PKT_STRIDE;
                if (tid < 192) {
                    int i = tid & 63;
                    u32 d0, d1, d2, d3;
                    for (;;) {
                        d0 = aload(base + 4 * i + 0);
                        d1 = aload(base + 4 * i + 1);
                        d2 = aload(base + 4 * i + 2);
                        d3 = aload(base + 4 * i + 3);
                        if (((((d0 >> 16) ^ ep) | ((d1 >> 16) ^ ep)) |
                             (((d2 >> 16) ^ ep) | ((d3 >> 16) ^ ep))) == 0) break;
                    }
                    if (i < 32) {          // m: j = 2i, 2i+1 (hi,lo dword pairs)
                        int idx = 64 * q2 + 2 * i;
                        mf[idx]         = hbits2f(d0) + hbits2f(d1);
                        m_hi16[idx]     = (u16)d0;  m_lo16[idx]     = (u16)d1;
                        mf[idx + 1]     = hbits2f(d2) + hbits2f(d3);
                        m_hi16[idx + 1] = (u16)d2;  m_lo16[idx + 1] = (u16)d3;
                    } else {               // h: c = 4i-128 .. +3
                        int idx = 128 * q2 + (4 * i - 128);
                        h_h16[idx]     = (u16)d0;
                        h_h16[idx + 1] = (u16)d1;
                        h_h16[idx + 2] = (u16)d2;
                        h_h16[idx + 3] = (u16)d3;
                    }
                } else {                   // u partial (hi/lo dwords)
                    u32 d0, d1;
                    for (;;) {
                        d0 = aload(base + 256);
                        d1 = aload(base + 257);
                        if ((((d0 >> 16) ^ ep) | ((d1 >> 16) ^ ep)) == 0) break;
                    }
                    upart[q2] = hbits2f(d0) + hbits2f(d1);
                }
            }
        }
        __syncthreads();                                   // B1

        // ---- z partials (old h, old m) + AT partials (old m) — all local ----
        {
            float z = 0.f;
            #pragma unroll
            for (int i = 0; i < 64; ++i)
                z = dot2f(h2u[64 * kg + i], hk_w[i], z);
            #pragma unroll
            for (int i = 0; i < 32; ++i) {
                u32 w = amk_w[i];
                z = dot2f(m_hi2[32 * kg + i], w, z);
                z = dot2f(m_lo2[32 * kg + i], w, z);
            }
            zbuf[tid] = z;
            float am = 0.f;
            #pragma unroll
            for (int i = 0; i < 32; ++i)
                am = fmaf(mf[32 * kg8 + i], at_w[i], am);
            ampart[tid] = am;
        }
        __syncthreads();                                   // B2

        // ---- finalize: u, m_new slice, h_new slice ----
        float u = 0.f, mnew = 0.f, hnew = 0.f;
        u16 mhi_b = 0, mlo_b = 0;
        if (tid < 128)
            u = upart[0] + upart[1] + upart[2] + upart[3] + xs[t] * ie0;
        if (tid < 64) {
            mnew = mf[J] + u * bt_sl[tid];
            #pragma unroll
            for (int gi = 0; gi < 8; ++gi) mnew += ampart[tid + 64 * gi];
            _Float16 hi = (_Float16)mnew;
            float lo = mnew - (float)hi;
            mhi_b = __builtin_bit_cast(u16, hi);
            mlo_b = f2h_bits(lo);
            mf[J] = mnew;            // own slice stays exact fp32
            m_hi16[J] = mhi_b;
            m_lo16[J] = mlo_b;
        }
        if (tid < 128) {
            float zf = zbuf[tid] + zbuf[tid + 128] + zbuf[tid + 256] + zbuf[tid + 384]
                     + xs[t] * ik_sl[tid] + u * bmk_sl[tid];
            hnew = tanhf(zf);
            outb[(size_t)t * N_UNITS + 128 * q + tid] = hnew;
            h_h16[128 * q + tid] = f2h_bits(hnew);
        }

        if (t < N_T - 1) {
            // ---- publish own slices (self-validating dwords, no drain/flag) ----
            const u32 eph = (u32)(t + 1) << 16;
            u32* myb = pkt + (size_t)((t & 1) * 256 + b * 4 + q) * PKT_STRIDE;
            if (tid < 64) {
                astore(myb + 2 * tid,     (u32)mhi_b | eph);
                astore(myb + 2 * tid + 1, (u32)mlo_b | eph);
            }
            if (tid < 128)
                astore(myb + 128 + tid, (u32)f2h_bits(hnew) | eph);

            // ---- own u-partial for step t+1 ----
            float up = 0.f;
            if (tid < 128) {
                up = hnew * he_sl[tid];
                if (tid < 64) up = fmaf(mnew, me_sl[tid], up);
            }
            #pragma unroll
            for (int off = 32; off > 0; off >>= 1) up += __shfl_down(up, off);
            if (lane == 0 && tid < 128) upw[tid >> 6] = up;
            __syncthreads();                               // B3
            if (tid == 0) {
                float myu = upw[0] + upw[1];
                upart[q] = myu;
                _Float16 hi = (_Float16)myu;
                float lo = myu - (float)hi;
                astore(myb + 256, (u32)__builtin_bit_cast(u16, hi) | eph);
                astore(myb + 257, (u32)f2h_bits(lo) | eph);
            }
        }
    }
}

extern "C" void kernel_launch(void* const* d_in, const int* in_sizes, int n_in,
                              void* d_out, int out_size, void* d_ws, size_t ws_size,
                              hipStream_t stream) {
    const float* x  = (const float*)d_in[0];
    const float* ie = (const float*)d_in[1];
    const float* he = (const float*)d_in[2];
    const float* me = (const float*)d_in[3];
    const float* ik = (const float*)d_in[4];
    const float* hk = (const float*)d_in[5];
    const float* mk = (const float*)d_in[6];
    const float* at = (const float*)d_in[7];
    const float* bt = (const float*)d_in[8];

    u32*   hk2  = (u32*)d_ws;                   // 131072 u32 = 512 KB
    u32*   amk2 = hk2 + 256 * 512;              //  65536 u32 = 256 KB
    float* bmk  = (float*)(amk2 + 128 * 512);   //    512 f32 =   2 KB
    u32*   pkt  = (u32*)(bmk + 512);            // 2*64*4*288 u32 = 576 KB

    prep_hk<<<512, 256, 0, stream>>>(hk, hk2);
    prep_amk<<<129, 512, 0, stream>>>(mk, at, bt, amk2, bmk);
    lmu_main<<<N_B * KWG, 512, 0, stream>>>(x, ie, he, me, ik, bt, at,
                                            hk2, amk2, bmk, pkt, (float*)d_out);
}